// Round 2
// baseline (1177.605 us; speedup 1.0000x reference)
//
#include <hip/hip_runtime.h>
#include <math.h>

#define BB 4
#define NN 6000
#define BN (BB*NN)      // 24000
#define SS 48
#define PQ (SS*SS)      // 2304
#define TT 550
#define TTP 552         // padded EV stride (16B-aligned rows)
#define HH 128

#define TPQ 64          // pq tile
#define TTILE 64        // t tile
#define KT 16           // k chunk
#define SPLITK 6        // 24000/6 = 4000, divisible by KT

__device__ __constant__ float kINV_2PI = 1.0f / (2.0f * 3.14159f);
__device__ __constant__ float kGAUSS_NORM = 0.3989422804f;

// ---------------- Kernel 1: MLP -> resp[bn] ----------------
__global__ __launch_bounds__(256) void mlp_kernel(
    const float* __restrict__ si, const float* __restrict__ mask,
    const float* __restrict__ W1, const float* __restrict__ b1,
    const float* __restrict__ W2, const float* __restrict__ b2,
    const float* __restrict__ W3, const float* __restrict__ b3,
    float* __restrict__ resp)
{
  __shared__ float sW2[HH * HH];
  __shared__ float sW1[2 * HH];
  __shared__ float sb1[HH], sb2[HH], sW3[HH];
  int tid = threadIdx.x;
  for (int i = tid; i < HH * HH; i += 256) sW2[i] = W2[i];
  if (tid < 2 * HH) sW1[tid] = W1[tid];
  if (tid < HH) { sb1[tid] = b1[tid]; sb2[tid] = b2[tid]; sW3[tid] = W3[tid]; }
  __syncthreads();
  int e = blockIdx.x * 256 + tid;
  if (e >= BN) return;
  float x0 = si[2 * e], x1 = si[2 * e + 1];
  float h1[HH];
  #pragma unroll
  for (int j = 0; j < HH; ++j)
    h1[j] = fmaxf(x0 * sW1[j] + x1 * sW1[HH + j] + sb1[j], 0.0f);
  float out = b3[0];
  for (int j = 0; j < HH; ++j) {
    // 4 partial sums for ILP (serial FMA chain otherwise)
    float a0 = sb2[j], a1 = 0.f, a2 = 0.f, a3 = 0.f;
    #pragma unroll
    for (int i = 0; i < HH; i += 4) {
      a0 += h1[i + 0] * sW2[(i + 0) * HH + j];
      a1 += h1[i + 1] * sW2[(i + 1) * HH + j];
      a2 += h1[i + 2] * sW2[(i + 2) * HH + j];
      a3 += h1[i + 3] * sW2[(i + 3) * HH + j];
    }
    float a = (a0 + a1) + (a2 + a3);
    out += fmaxf(a, 0.0f) * sW3[j];
  }
  resp[e] = expf(out) * mask[e];
}

// ---------------- Kernel 2: GxR[bn][p], Gy[bn][q] ----------------
__global__ __launch_bounds__(256) void gxy_kernel(
    const float* __restrict__ si, const float* __restrict__ sensor,
    const float* __restrict__ resp, const float* __restrict__ el_spread,
    float* __restrict__ GxR, float* __restrict__ Gy)
{
  int idx = blockIdx.x * 256 + threadIdx.x;  // bn*48 + p
  if (idx >= BN * SS) return;
  int bn = idx / SS;
  int p = idx - bn * SS;
  float es = el_spread[0];
  float var = es * es;
  float inv2v = 0.5f / var;
  float lp = sensor[p * SS * 2];  // lin[p] = sensor_locations[p][0][0]
  float x = si[2 * bn], y = si[2 * bn + 1];
  float dx = x - lp, dy = y - lp;
  GxR[idx] = expf(-dx * dx * inv2v) * resp[bn] * (kINV_2PI / var);
  Gy[idx]  = expf(-dy * dy * inv2v);
}

// ---------------- Kernel 3: EV[bn][t] (padded stride 552, pad=0) ----------------
__global__ __launch_bounds__(256) void ev_kernel(
    const float* __restrict__ zpos, const float* __restrict__ nn_bin_sigma,
    float* __restrict__ EV)
{
  int bn = blockIdx.x;
  float z = zpos[bn];
  float s = nn_bin_sigma[0];
  float bs = s * s;
  float inv2bs = 0.5f / bs;
  float scale = kGAUSS_NORM / sqrtf(bs);
  for (int t = threadIdx.x; t < TTP; t += 256) {
    float v = 0.0f;
    if (t < TT) {
      float d = (float)t - z;
      v = expf(-d * d * inv2bs) * scale;
    }
    EV[bn * TTP + t] = v;
  }
}

// ---------------- Kernel 4: zero the output ----------------
__global__ __launch_bounds__(256) void zero_kernel(float* __restrict__ out, int n)
{
  int i = blockIdx.x * 256 + threadIdx.x;
  if (i < n) out[i] = 0.0f;
}

// ---------------- Kernel 5: tiled contraction ----------------
// out[pq][t] += sum_k GxR[k][pq/48] * Gy[k][pq%48] * EV[k][t]
__global__ __launch_bounds__(256) void gemm_kernel(
    const float* __restrict__ GxR, const float* __restrict__ Gy,
    const float* __restrict__ EV, float* __restrict__ out)
{
  __shared__ __attribute__((aligned(16))) float Asm[KT][TPQ];
  __shared__ __attribute__((aligned(16))) float Esm[KT][TTILE];

  int tid = threadIdx.x;
  int pqBase = blockIdx.x * TPQ;
  int tBase  = blockIdx.y * TTILE;
  int k0 = blockIdx.z * (BN / SPLITK);
  int k1 = k0 + (BN / SPLITK);

  int tx = tid & 15;        // t micro index
  int ty = tid >> 4;        // pq micro index
  int sK  = tid >> 4;       // staging row 0..15
  int sC4 = (tid & 15) * 4; // staging col (x4)

  float acc[4][4] = {};

  for (int kc = k0; kc < k1; kc += KT) {
    // stage A tile: Asm[k][c] = GxR[k][p(c)] * Gy[k][q(c)]
    {
      float av[4];
      #pragma unroll
      for (int i = 0; i < 4; ++i) {
        int pq = pqBase + sC4 + i;
        int p = pq / SS;
        int q = pq - p * SS;
        av[i] = GxR[(kc + sK) * SS + p] * Gy[(kc + sK) * SS + q];
      }
      *(float4*)&Asm[sK][sC4] = make_float4(av[0], av[1], av[2], av[3]);
    }
    // stage EV tile
    {
      int t = tBase + sC4;
      float4 v = make_float4(0.f, 0.f, 0.f, 0.f);
      if (t <= TTP - 4) v = *(const float4*)&EV[(kc + sK) * TTP + t];
      *(float4*)&Esm[sK][sC4] = v;
    }
    __syncthreads();
    #pragma unroll
    for (int k = 0; k < KT; ++k) {
      float4 a = *(const float4*)&Asm[k][ty * 4];
      float4 e = *(const float4*)&Esm[k][tx * 4];
      acc[0][0] += a.x * e.x; acc[0][1] += a.x * e.y; acc[0][2] += a.x * e.z; acc[0][3] += a.x * e.w;
      acc[1][0] += a.y * e.x; acc[1][1] += a.y * e.y; acc[1][2] += a.y * e.z; acc[1][3] += a.y * e.w;
      acc[2][0] += a.z * e.x; acc[2][1] += a.z * e.y; acc[2][2] += a.z * e.z; acc[2][3] += a.z * e.w;
      acc[3][0] += a.w * e.x; acc[3][1] += a.w * e.y; acc[3][2] += a.w * e.z; acc[3][3] += a.w * e.w;
    }
    __syncthreads();
  }

  // epilogue: atomic accumulate (SPLITK partial sums)
  #pragma unroll
  for (int i = 0; i < 4; ++i) {
    int pq = pqBase + ty * 4 + i;
    #pragma unroll
    for (int j = 0; j < 4; ++j) {
      int t = tBase + tx * 4 + j;
      if (t < TT) atomicAdd(&out[pq * TT + t], acc[i][j]);
    }
  }
}

extern "C" void kernel_launch(void* const* d_in, const int* in_sizes, int n_in,
                              void* d_out, int out_size, void* d_ws, size_t ws_size,
                              hipStream_t stream) {
  const float* si     = (const float*)d_in[0];   // [B,N,2]
  const float* zpos   = (const float*)d_in[1];   // [B,N]
  const float* mask   = (const float*)d_in[2];   // [B,N,1]
  const float* sensor = (const float*)d_in[3];   // [S,S,2]
  const float* W1     = (const float*)d_in[4];
  const float* b1     = (const float*)d_in[5];
  const float* W2     = (const float*)d_in[6];
  const float* b2     = (const float*)d_in[7];
  const float* W3     = (const float*)d_in[8];
  const float* b3     = (const float*)d_in[9];
  const float* el_spread    = (const float*)d_in[10];
  const float* nn_bin_sigma = (const float*)d_in[11];
  float* out = (float*)d_out;

  // workspace layout (floats)
  float* ws   = (float*)d_ws;
  float* resp = ws;                         // 24000
  float* GxR  = resp + BN;                  // 24000*48
  float* Gy   = GxR + BN * SS;              // 24000*48
  float* EV   = Gy + BN * SS;               // 24000*552

  mlp_kernel<<<(BN + 255) / 256, 256, 0, stream>>>(si, mask, W1, b1, W2, b2, W3, b3, resp);
  gxy_kernel<<<(BN * SS + 255) / 256, 256, 0, stream>>>(si, sensor, resp, el_spread, GxR, Gy);
  ev_kernel<<<BN, 256, 0, stream>>>(zpos, nn_bin_sigma, EV);
  zero_kernel<<<(PQ * TT + 255) / 256, 256, 0, stream>>>(out, PQ * TT);
  gemm_kernel<<<dim3(PQ / TPQ, (TT + TTILE - 1) / TTILE, SPLITK), 256, 0, stream>>>(GxR, Gy, EV, out);
}

// Round 3
// 505.106 us; speedup vs baseline: 2.3314x; 2.3314x over previous
//
#include <hip/hip_runtime.h>
#include <math.h>

#define BB 4
#define NN 6000
#define BN (BB*NN)      // 24000
#define SS 48
#define PQ (SS*SS)      // 2304
#define TT 550
#define HH 128

#define TPQ 64          // pq tile
#define TTILE 64        // t tile
#define NTILES 9        // ceil(550/64)
#define KT 16           // k chunk
#define SPLITK 6
#define CAP BN          // per-tile list capacity (worst case: all electrons)

__device__ __constant__ float kINV_2PI = 1.0f / (2.0f * 3.14159f);
__device__ __constant__ float kGAUSS_NORM = 0.3989422804f;

// ---------------- Kernel 1: MLP -> resp[bn] ----------------
__global__ __launch_bounds__(256) void mlp_kernel(
    const float* __restrict__ si, const float* __restrict__ mask,
    const float* __restrict__ W1, const float* __restrict__ b1,
    const float* __restrict__ W2, const float* __restrict__ b2,
    const float* __restrict__ W3, const float* __restrict__ b3,
    float* __restrict__ resp)
{
  __shared__ float sW2[HH * HH];
  __shared__ float sW1[2 * HH];
  __shared__ float sb1[HH], sb2[HH], sW3[HH];
  int tid = threadIdx.x;
  for (int i = tid; i < HH * HH; i += 256) sW2[i] = W2[i];
  if (tid < 2 * HH) sW1[tid] = W1[tid];
  if (tid < HH) { sb1[tid] = b1[tid]; sb2[tid] = b2[tid]; sW3[tid] = W3[tid]; }
  __syncthreads();
  int e = blockIdx.x * 256 + tid;
  if (e >= BN) return;
  float x0 = si[2 * e], x1 = si[2 * e + 1];
  float h1[HH];
  #pragma unroll
  for (int j = 0; j < HH; ++j)
    h1[j] = fmaxf(x0 * sW1[j] + x1 * sW1[HH + j] + sb1[j], 0.0f);
  float out = b3[0];
  for (int j = 0; j < HH; ++j) {
    float a0 = sb2[j], a1 = 0.f, a2 = 0.f, a3 = 0.f;
    #pragma unroll
    for (int i = 0; i < HH; i += 4) {
      a0 += h1[i + 0] * sW2[(i + 0) * HH + j];
      a1 += h1[i + 1] * sW2[(i + 1) * HH + j];
      a2 += h1[i + 2] * sW2[(i + 2) * HH + j];
      a3 += h1[i + 3] * sW2[(i + 3) * HH + j];
    }
    float a = (a0 + a1) + (a2 + a3);
    out += fmaxf(a, 0.0f) * sW3[j];
  }
  resp[e] = expf(out) * mask[e];
}

// ---------------- Kernel 2: GxR[bn][p], Gy[bn][q] ----------------
__global__ __launch_bounds__(256) void gxy_kernel(
    const float* __restrict__ si, const float* __restrict__ sensor,
    const float* __restrict__ resp, const float* __restrict__ el_spread,
    float* __restrict__ GxR, float* __restrict__ Gy)
{
  int idx = blockIdx.x * 256 + threadIdx.x;  // bn*48 + p
  if (idx >= BN * SS) return;
  int bn = idx / SS;
  int p = idx - bn * SS;
  float es = el_spread[0];
  float var = es * es;
  float inv2v = 0.5f / var;
  float lp = sensor[p * SS * 2];  // lin[p] = sensor_locations[p][0][0]
  float x = si[2 * bn], y = si[2 * bn + 1];
  float dx = x - lp, dy = y - lp;
  GxR[idx] = expf(-dx * dx * inv2v) * resp[bn] * (kINV_2PI / var);
  Gy[idx]  = expf(-dy * dy * inv2v);
}

// ---------------- Kernel 3: zero a float buffer ----------------
__global__ __launch_bounds__(256) void zero_kernel(float* __restrict__ out, int n)
{
  int i = blockIdx.x * 256 + threadIdx.x;
  if (i < n) out[i] = 0.0f;
}

// ---------------- Kernel 4: bin electrons into t-tiles ----------------
// electron bn contributes to tile j iff [z-W, z+W] overlaps [64j, 64j+63]
__global__ __launch_bounds__(256) void bin_kernel(
    const float* __restrict__ zpos, const float* __restrict__ nn_bin_sigma,
    int* __restrict__ counts, int* __restrict__ kidx, float* __restrict__ kz)
{
  int bn = blockIdx.x * 256 + threadIdx.x;
  if (bn >= BN) return;
  float s = nn_bin_sigma[0];
  float bs = s * s;
  // drop where d^2/(2 bs) > 64  ->  ev suppressed by e^-64 ~ 1.6e-28
  float W = ceilf(sqrtf(128.0f * bs));
  float z = zpos[bn];
  int jlo = (int)floorf((z - W) * (1.0f / TTILE));
  int jhi = (int)floorf((z + W) * (1.0f / TTILE));
  if (jlo < 0) jlo = 0;
  if (jhi > NTILES - 1) jhi = NTILES - 1;
  for (int j = jlo; j <= jhi; ++j) {
    int slot = atomicAdd(&counts[j], 1);
    kidx[j * CAP + slot] = bn;
    kz[j * CAP + slot] = z;
  }
}

// ---------------- Kernel 5: tiled contraction over per-tile electron lists ----
// out[pq][t] += sum_{k in list[tileT]} GxR[k][p]*Gy[k][q] * ev(t, z_k)
__global__ __launch_bounds__(256) void gemm_kernel(
    const float* __restrict__ GxR, const float* __restrict__ Gy,
    const int* __restrict__ counts, const int* __restrict__ kidx,
    const float* __restrict__ kz, const float* __restrict__ nn_bin_sigma,
    float* __restrict__ out)
{
  __shared__ __attribute__((aligned(16))) float Asm[KT][TPQ];
  __shared__ __attribute__((aligned(16))) float Esm[KT][TTILE];

  int tid = threadIdx.x;
  int pqBase = blockIdx.x * TPQ;
  int tileT = blockIdx.y;
  int tBase = tileT * TTILE;

  float s = nn_bin_sigma[0];
  float bs = s * s;
  float inv2bs = 0.5f / bs;
  float scale = kGAUSS_NORM / sqrtf(bs);

  int count = counts[tileT];
  int chunks = (count + KT - 1) / KT;
  int cps = (chunks + SPLITK - 1) / SPLITK;       // chunks per split
  int k0 = blockIdx.z * cps * KT;
  int k1 = count < k0 + cps * KT ? count : k0 + cps * KT;
  if (k0 >= k1) return;                            // empty split: acc would be 0

  const int* __restrict__ myidx = kidx + tileT * CAP;
  const float* __restrict__ myz = kz + tileT * CAP;

  int tx = tid & 15;        // t micro index
  int ty = tid >> 4;        // pq micro index
  int sK  = tid >> 4;       // staging row 0..15
  int sC4 = (tid & 15) * 4; // staging col (x4)

  float acc[4][4] = {};

  for (int kc = k0; kc < k1; kc += KT) {
    int k = kc + sK;
    float av[4] = {0.f, 0.f, 0.f, 0.f};
    float ev[4] = {0.f, 0.f, 0.f, 0.f};
    if (k < k1) {
      int idx = myidx[k];
      float z = myz[k];
      #pragma unroll
      for (int i = 0; i < 4; ++i) {
        int pq = pqBase + sC4 + i;
        int p = pq / SS;
        int q = pq - p * SS;
        av[i] = GxR[idx * SS + p] * Gy[idx * SS + q];
      }
      #pragma unroll
      for (int i = 0; i < 4; ++i) {
        int t = tBase + sC4 + i;
        if (t < TT) {
          float d = (float)t - z;
          ev[i] = expf(-d * d * inv2bs) * scale;
        }
      }
    }
    *(float4*)&Asm[sK][sC4] = make_float4(av[0], av[1], av[2], av[3]);
    *(float4*)&Esm[sK][sC4] = make_float4(ev[0], ev[1], ev[2], ev[3]);
    __syncthreads();
    #pragma unroll
    for (int k2 = 0; k2 < KT; ++k2) {
      float4 a = *(const float4*)&Asm[k2][ty * 4];
      float4 e = *(const float4*)&Esm[k2][tx * 4];
      acc[0][0] += a.x * e.x; acc[0][1] += a.x * e.y; acc[0][2] += a.x * e.z; acc[0][3] += a.x * e.w;
      acc[1][0] += a.y * e.x; acc[1][1] += a.y * e.y; acc[1][2] += a.y * e.z; acc[1][3] += a.y * e.w;
      acc[2][0] += a.z * e.x; acc[2][1] += a.z * e.y; acc[2][2] += a.z * e.z; acc[2][3] += a.z * e.w;
      acc[3][0] += a.w * e.x; acc[3][1] += a.w * e.y; acc[3][2] += a.w * e.z; acc[3][3] += a.w * e.w;
    }
    __syncthreads();
  }

  #pragma unroll
  for (int i = 0; i < 4; ++i) {
    int pq = pqBase + ty * 4 + i;
    #pragma unroll
    for (int j = 0; j < 4; ++j) {
      int t = tBase + tx * 4 + j;
      if (t < TT) atomicAdd(&out[pq * TT + t], acc[i][j]);
    }
  }
}

extern "C" void kernel_launch(void* const* d_in, const int* in_sizes, int n_in,
                              void* d_out, int out_size, void* d_ws, size_t ws_size,
                              hipStream_t stream) {
  const float* si     = (const float*)d_in[0];   // [B,N,2]
  const float* zpos   = (const float*)d_in[1];   // [B,N]
  const float* mask   = (const float*)d_in[2];   // [B,N,1]
  const float* sensor = (const float*)d_in[3];   // [S,S,2]
  const float* W1     = (const float*)d_in[4];
  const float* b1     = (const float*)d_in[5];
  const float* W2     = (const float*)d_in[6];
  const float* b2     = (const float*)d_in[7];
  const float* W3     = (const float*)d_in[8];
  const float* b3     = (const float*)d_in[9];
  const float* el_spread    = (const float*)d_in[10];
  const float* nn_bin_sigma = (const float*)d_in[11];
  float* out = (float*)d_out;

  // workspace layout
  float* ws    = (float*)d_ws;
  float* resp  = ws;                        // 24000
  float* GxR   = resp + BN;                 // 24000*48
  float* Gy    = GxR + BN * SS;             // 24000*48
  float* kz    = Gy + BN * SS;              // 9*24000
  int*   counts = (int*)(kz + NTILES * CAP);      // 16 (padded)
  int*   kidx   = counts + 16;                     // 9*24000

  mlp_kernel<<<(BN + 255) / 256, 256, 0, stream>>>(si, mask, W1, b1, W2, b2, W3, b3, resp);
  gxy_kernel<<<(BN * SS + 255) / 256, 256, 0, stream>>>(si, sensor, resp, el_spread, GxR, Gy);
  zero_kernel<<<(PQ * TT + 255) / 256, 256, 0, stream>>>(out, PQ * TT);
  zero_kernel<<<1, 256, 0, stream>>>((float*)counts, 16);   // ws is re-poisoned each call
  bin_kernel<<<(BN + 255) / 256, 256, 0, stream>>>(zpos, nn_bin_sigma, counts, kidx, kz);
  gemm_kernel<<<dim3(PQ / TPQ, NTILES, SPLITK), 256, 0, stream>>>(
      GxR, Gy, counts, kidx, kz, nn_bin_sigma, out);
}

// Round 6
// 370.087 us; speedup vs baseline: 3.1820x; 1.3648x over previous
//
#include <hip/hip_runtime.h>
#include <math.h>

#define BB 4
#define NN 6000
#define BN (BB*NN)      // 24000
#define SS 48
#define PQ (SS*SS)      // 2304
#define TT 550
#define HH 128

#define TPQ 128         // pq tile
#define TTILE 64        // t tile
#define NTILES 9        // ceil(550/64)
#define KT 16           // k chunk
#define SPLITK 6
#define CAP2 (BN + 96)  // per-tile list capacity incl. padding
#define MLP_E 64        // electrons per MLP block

__device__ __constant__ float kINV_2PI = 1.0f / (2.0f * 3.14159f);
__device__ __constant__ float kGAUSS_NORM = 0.3989422804f;
#define LOG2E 1.4426950408889634f

__device__ __forceinline__ float fexp2(float x) { return __builtin_amdgcn_exp2f(x); }

// ---------------- Kernel 1: batched MLP -> resp[bn] ----------------
// 64 electrons per block; W2 staged once; layer2 is an 8e x 4c register tile.
__global__ __launch_bounds__(256) void mlp_kernel(
    const float* __restrict__ si, const float* __restrict__ mask,
    const float* __restrict__ W1, const float* __restrict__ b1,
    const float* __restrict__ W2, const float* __restrict__ b2,
    const float* __restrict__ W3, const float* __restrict__ b3,
    float* __restrict__ resp)
{
  __shared__ float sW2[HH * HH];          // 64 KB
  __shared__ float sh1T[HH][MLP_E];       // 32 KB, [i][e]
  __shared__ float sW1[2 * HH];
  __shared__ float sb1[HH], sb2[HH], sW3[HH];
  int tid = threadIdx.x;
  for (int i = tid * 4; i < HH * HH; i += 1024)
    *(float4*)&sW2[i] = *(const float4*)&W2[i];
  if (tid < 2 * HH) sW1[tid] = W1[tid];
  if (tid < HH) { sb1[tid] = b1[tid]; sb2[tid] = b2[tid]; sW3[tid] = W3[tid]; }
  int e0 = blockIdx.x * MLP_E;
  int e = tid & 63;
  float x0 = si[2 * (e0 + e)], x1 = si[2 * (e0 + e) + 1];
  __syncthreads();
  // layer 1: wave-uniform j, lane = electron
  int jb = (tid >> 6) * 32;
  #pragma unroll
  for (int jj = 0; jj < 32; ++jj) {
    int j = jb + jj;
    sh1T[j][e] = fmaxf(x0 * sW1[j] + x1 * sW1[HH + j] + sb1[j], 0.0f);
  }
  __syncthreads();
  // layer 2 + 3: thread = (e-group of 8) x (4 cols)
  int c4 = (tid & 31) * 4;
  int eh = tid >> 5;  // 0..7
  float acc[8][4] = {};
  for (int i = 0; i < HH; ++i) {
    float4 w  = *(const float4*)&sW2[i * HH + c4];
    float4 ha = *(const float4*)&sh1T[i][eh * 8];
    float4 hb = *(const float4*)&sh1T[i][eh * 8 + 4];
    float hv[8] = {ha.x, ha.y, ha.z, ha.w, hb.x, hb.y, hb.z, hb.w};
    #pragma unroll
    for (int ee = 0; ee < 8; ++ee) {
      acc[ee][0] += hv[ee] * w.x; acc[ee][1] += hv[ee] * w.y;
      acc[ee][2] += hv[ee] * w.z; acc[ee][3] += hv[ee] * w.w;
    }
  }
  float outp[8];
  #pragma unroll
  for (int ee = 0; ee < 8; ++ee) {
    float sacc = 0.0f;
    #pragma unroll
    for (int cc = 0; cc < 4; ++cc)
      sacc += fmaxf(acc[ee][cc] + sb2[c4 + cc], 0.0f) * sW3[c4 + cc];
    outp[ee] = sacc;
  }
  // reduce over the 32 c-groups (consecutive 32 lanes share an e-group)
  #pragma unroll
  for (int off = 1; off < 32; off <<= 1)
    #pragma unroll
    for (int ee = 0; ee < 8; ++ee)
      outp[ee] += __shfl_xor(outp[ee], off);
  if ((tid & 31) == 0) {
    float b3v = b3[0];
    #pragma unroll
    for (int ee = 0; ee < 8; ++ee) {
      int eidx = e0 + eh * 8 + ee;
      resp[eidx] = fexp2((outp[ee] + b3v) * LOG2E) * mask[eidx];
    }
  }
}

// ---------------- Kernel 2: GxR[bn][p], Gy[bn][q] ----------------
// temporal scale (GAUSS_NORM/sqrt(bs)) folded into GxR
__global__ __launch_bounds__(256) void gxy_kernel(
    const float* __restrict__ si, const float* __restrict__ sensor,
    const float* __restrict__ resp, const float* __restrict__ el_spread,
    const float* __restrict__ nn_bin_sigma,
    float* __restrict__ GxR, float* __restrict__ Gy)
{
  int idx = blockIdx.x * 256 + threadIdx.x;  // bn*48 + p
  if (idx >= BN * SS) return;
  int bn = idx / SS;
  int p = idx - bn * SS;
  float es = el_spread[0];
  float var = es * es;
  float c = (0.5f / var) * LOG2E;
  float sb = nn_bin_sigma[0];
  float bs = sb * sb;
  float tscale = kGAUSS_NORM / sqrtf(bs);
  float lp = sensor[p * SS * 2];
  float x = si[2 * bn], y = si[2 * bn + 1];
  float dx = x - lp, dy = y - lp;
  GxR[idx] = fexp2(-dx * dx * c) * resp[bn] * (kINV_2PI / var) * tscale;
  Gy[idx]  = fexp2(-dy * dy * c);
}

// ---------------- Kernel 3: zero a buffer ----------------
__global__ __launch_bounds__(256) void zero_kernel(float* __restrict__ out, int n)
{
  int i = blockIdx.x * 256 + threadIdx.x;
  if (i < n) out[i] = 0.0f;
}

// ---------------- Kernel 4: bin electrons (wave-aggregated atomics) ----------
__global__ __launch_bounds__(256) void bin_kernel(
    const float* __restrict__ zpos, const float* __restrict__ nn_bin_sigma,
    int* __restrict__ counts, int* __restrict__ kidx, float* __restrict__ kz)
{
  int bn = blockIdx.x * 256 + threadIdx.x;
  if (bn >= BN) return;  // BN % 64 == 0: whole waves exit together
  float s = nn_bin_sigma[0];
  float bs = s * s;
  float W = ceilf(sqrtf(128.0f * bs));  // drop terms suppressed by <= e^-64
  float z = zpos[bn];
  int jlo = (int)floorf((z - W) * (1.0f / TTILE));
  int jhi = (int)floorf((z + W) * (1.0f / TTILE));
  jlo = jlo < 0 ? 0 : jlo;
  jhi = jhi > NTILES - 1 ? NTILES - 1 : jhi;
  int lane = threadIdx.x & 63;
  for (int j = 0; j < NTILES; ++j) {
    bool c = (j >= jlo) && (j <= jhi);
    unsigned long long m = __ballot(c);
    if (m == 0ull) continue;
    int leader = __ffsll((unsigned long long)m) - 1;
    int base = 0;
    if (lane == leader) base = atomicAdd(&counts[j], __popcll(m));
    base = __shfl(base, leader);
    if (c) {
      int slot = base + __popcll(m & ((1ull << lane) - 1ull));
      kidx[j * CAP2 + slot] = bn;
      kz[j * CAP2 + slot] = z;
    }
  }
}

// ---------------- Kernel 5: pad lists to multiple of KT*SPLITK ----------------
__global__ __launch_bounds__(256) void pad_kernel(
    int* __restrict__ counts, int* __restrict__ kidx, float* __restrict__ kz)
{
  int j = blockIdx.x;  // 9 blocks
  int c = counts[j];
  __syncthreads();
  int pc = ((c + KT * SPLITK - 1) / (KT * SPLITK)) * (KT * SPLITK);
  for (int ss = c + threadIdx.x; ss < pc; ss += 256) {
    kidx[j * CAP2 + ss] = 0;        // valid address; contribution killed by ev=0
    kz[j * CAP2 + ss] = -1.0e6f;    // exp2 underflows to exactly 0
  }
  if (threadIdx.x == 0) counts[j] = pc;
}

// ---------------- Kernel 6: tiled contraction, 128pq x 64t, 8x4 micro --------
__global__ __launch_bounds__(256) void gemm_kernel(
    const float* __restrict__ GxR, const float* __restrict__ Gy,
    const int* __restrict__ counts, const int* __restrict__ kidx,
    const float* __restrict__ kz, const float* __restrict__ nn_bin_sigma,
    float* __restrict__ out)
{
  __shared__ __attribute__((aligned(16))) float Asm[KT][TPQ];   // 8 KB
  __shared__ __attribute__((aligned(16))) float Esm[KT][TTILE]; // 4 KB

  int tid = threadIdx.x;
  int pqBase = blockIdx.x * TPQ;
  int tileT = blockIdx.y;
  int tBase = tileT * TTILE;

  float s = nn_bin_sigma[0];
  float c2 = (0.5f * LOG2E) / (s * s);

  int count = counts[tileT];               // padded: divisible by KT*SPLITK
  int cps = count / (KT * SPLITK);         // chunks per split
  int k0 = blockIdx.z * cps * KT;
  int k1 = k0 + cps * KT;
  if (k0 >= k1) return;

  const int* __restrict__ myidx = kidx + tileT * CAP2;
  const float* __restrict__ myz = kz + tileT * CAP2;

  int sK = tid >> 4;          // staging k row 0..15
  int aC = (tid & 15) * 8;    // A staging col
  int eC = (tid & 15) * 4;    // E staging col
  int tpq = (tid >> 4) * 8;   // compute pq base
  int tt  = (tid & 15) * 4;   // compute t base

  float acc[8][4] = {};

  for (int kc = k0; kc < k1; kc += KT) {
    int k = kc + sK;
    int idx = myidx[k];
    float z = myz[k];
    float av[8];
    #pragma unroll
    for (int i = 0; i < 8; ++i) {
      int pq = pqBase + aC + i;
      int p = pq / SS;
      int q = pq - p * SS;
      av[i] = GxR[idx * SS + p] * Gy[idx * SS + q];
    }
    float ev[4];
    #pragma unroll
    for (int i = 0; i < 4; ++i) {
      float d = (float)(tBase + eC + i) - z;
      ev[i] = fexp2(-d * d * c2);
    }
    *(float4*)&Asm[sK][aC]     = make_float4(av[0], av[1], av[2], av[3]);
    *(float4*)&Asm[sK][aC + 4] = make_float4(av[4], av[5], av[6], av[7]);
    *(float4*)&Esm[sK][eC]     = make_float4(ev[0], ev[1], ev[2], ev[3]);
    __syncthreads();
    #pragma unroll
    for (int k2 = 0; k2 < KT; ++k2) {
      float4 a0 = *(const float4*)&Asm[k2][tpq];
      float4 a1 = *(const float4*)&Asm[k2][tpq + 4];
      float4 e4 = *(const float4*)&Esm[k2][tt];
      float aa[8] = {a0.x, a0.y, a0.z, a0.w, a1.x, a1.y, a1.z, a1.w};
      float ee[4] = {e4.x, e4.y, e4.z, e4.w};
      #pragma unroll
      for (int i2 = 0; i2 < 8; ++i2)
        #pragma unroll
        for (int j2 = 0; j2 < 4; ++j2)
          acc[i2][j2] += aa[i2] * ee[j2];
    }
    __syncthreads();
  }

  #pragma unroll
  for (int i = 0; i < 8; ++i) {
    int pq = pqBase + tpq + i;
    #pragma unroll
    for (int j = 0; j < 4; ++j) {
      int t = tBase + tt + j;
      if (t < TT) atomicAdd(&out[pq * TT + t], acc[i][j]);
    }
  }
}

extern "C" void kernel_launch(void* const* d_in, const int* in_sizes, int n_in,
                              void* d_out, int out_size, void* d_ws, size_t ws_size,
                              hipStream_t stream) {
  const float* si     = (const float*)d_in[0];
  const float* zpos   = (const float*)d_in[1];
  const float* mask   = (const float*)d_in[2];
  const float* sensor = (const float*)d_in[3];
  const float* W1     = (const float*)d_in[4];
  const float* b1     = (const float*)d_in[5];
  const float* W2     = (const float*)d_in[6];
  const float* b2     = (const float*)d_in[7];
  const float* W3     = (const float*)d_in[8];
  const float* b3     = (const float*)d_in[9];
  const float* el_spread    = (const float*)d_in[10];
  const float* nn_bin_sigma = (const float*)d_in[11];
  float* out = (float*)d_out;

  float* ws    = (float*)d_ws;
  float* resp  = ws;                          // 24000
  float* GxR   = resp + BN;                   // 24000*48
  float* Gy    = GxR + BN * SS;               // 24000*48
  float* kz    = Gy + BN * SS;                // 9*CAP2
  int*   counts = (int*)(kz + NTILES * CAP2); // 16
  int*   kidx   = counts + 16;                // 9*CAP2

  mlp_kernel<<<BN / MLP_E, 256, 0, stream>>>(si, mask, W1, b1, W2, b2, W3, b3, resp);
  gxy_kernel<<<(BN * SS + 255) / 256, 256, 0, stream>>>(si, sensor, resp, el_spread,
                                                        nn_bin_sigma, GxR, Gy);
  zero_kernel<<<(PQ * TT + 255) / 256, 256, 0, stream>>>(out, PQ * TT);
  zero_kernel<<<1, 256, 0, stream>>>((float*)counts, 16);
  bin_kernel<<<(BN + 255) / 256, 256, 0, stream>>>(zpos, nn_bin_sigma, counts, kidx, kz);
  pad_kernel<<<NTILES, 256, 0, stream>>>(counts, kidx, kz);
  gemm_kernel<<<dim3(PQ / TPQ, NTILES, SPLITK), 256, 0, stream>>>(
      GxR, Gy, counts, kidx, kz, nn_bin_sigma, out);
}